// Round 9
// baseline (314.976 us; speedup 1.0000x reference)
//
#include <hip/hip_runtime.h>

#define N_ROWS 32768
#define D_IN 320
#define CB 16
#define N_BOOKS 8192

typedef __attribute__((ext_vector_type(8))) short bf16x8;
typedef __attribute__((ext_vector_type(4))) float f32x4;
#define MFMA __builtin_amdgcn_mfma_f32_16x16x32_bf16
#define AS1 __attribute__((address_space(1)))
#define AS3 __attribute__((address_space(3)))

__device__ __forceinline__ unsigned short bf16rn(float f) {
  unsigned u = __float_as_uint(f);
  u += 0x7fffu + ((u >> 16) & 1u);
  return (unsigned short)(u >> 16);
}
__device__ __forceinline__ float bf16tof(unsigned short h) {
  return __uint_as_float(((unsigned)h) << 16);
}
__device__ __forceinline__ void gload_lds16(const short* g, short* l) {
  __builtin_amdgcn_global_load_lds((const AS1 unsigned int*)g, (AS3 unsigned int*)l, 16, 0, 0);
}
// atomic max for non-negative floats via int-bit ordering
__device__ __forceinline__ void atomicMaxPosF(int* addr, float v) {
  atomicMax(addr, __float_as_int(v));
}

// ================= Kernel A: fused prep (codebook 2-split frag-pack) + proj =================
// blocks 0..31: prep. Per 16-book tile bt: 512 shorts = lo1|hi1 (B1 dedup) + lo2|hi2 (B2 dedup).
// MFMA B-frag upper 32 lanes duplicate lower 32 -> read with (lane&31): free 2-way broadcast.
// Also atomicMax of ||c||^2 into gmaxC2.
// blocks 32..543: proj = X @ W^T via bf16 3-split MFMA, fp64 flush; writes
//   tsplit[row][32] = t1[16]|t2[16]; atomicMax of ||t||^2 into gmaxT2.
__global__ __launch_bounds__(256, 2) void prep_proj_kernel(const float* __restrict__ cbk,
                                                           const float* __restrict__ x,
                                                           const float* __restrict__ w,
                                                           short* __restrict__ bfrag,
                                                           float* __restrict__ nh_g,
                                                           short* __restrict__ tsplit,
                                                           int* __restrict__ gmaxT2,
                                                           int* __restrict__ gmaxC2) {
  __shared__ __align__(16) short wfrag[3][10][64][8];  // 30720 B
  __shared__ __align__(16) float xs[2][64 * 36];       // 18432 B
  __shared__ float wred[4];
  const int tid = threadIdx.x;

  if (blockIdx.x < 32) {  // ---------- prep ----------
    const int j = blockIdx.x * 256 + tid;
    const float4* src = (const float4*)(cbk + (size_t)j * CB);
    float4 a = src[0], b = src[1], c = src[2], d = src[3];
    float ce[16] = {a.x, a.y, a.z, a.w, b.x, b.y, b.z, b.w,
                    c.x, c.y, c.z, c.w, d.x, d.y, d.z, d.w};
    short c1[16], c2[16];
    double s = 0.0;
#pragma unroll
    for (int i = 0; i < 16; i++) {
      s += (double)ce[i] * (double)ce[i];
      unsigned short x1 = bf16rn(ce[i]);
      float r1 = ce[i] - bf16tof(x1);
      unsigned short x2 = bf16rn(r1);
      c1[i] = (short)x1; c2[i] = (short)x2;
    }
    nh_g[j] = (float)(-0.5 * s);
    bf16x8 lo1, hi1, lo2, hi2;
#pragma unroll
    for (int i = 0; i < 8; i++) {
      lo1[i] = c1[i]; hi1[i] = c1[i + 8];
      lo2[i] = c2[i]; hi2[i] = c2[i + 8];
    }
    short* base = bfrag + (size_t)(j >> 4) * 512;
    const int n = j & 15;
    *(bf16x8*)(base + 0 + n * 8) = lo1;
    *(bf16x8*)(base + 128 + n * 8) = hi1;
    *(bf16x8*)(base + 256 + n * 8) = lo2;
    *(bf16x8*)(base + 384 + n * 8) = hi2;
    // block-reduce max ||c||^2 -> one atomic per block
    float c2f = (float)s;
#pragma unroll
    for (int msk = 1; msk <= 32; msk <<= 1) c2f = fmaxf(c2f, __shfl_xor(c2f, msk));
    if ((tid & 63) == 0) wred[tid >> 6] = c2f;
    __syncthreads();
    if (tid == 0)
      atomicMaxPosF(gmaxC2, fmaxf(fmaxf(wred[0], wred[1]), fmaxf(wred[2], wred[3])));
    return;
  }

  // ---------- proj ----------
  const int bid = blockIdx.x - 32;
  const int lane = tid & 63;
  const int wv = tid >> 6;

  for (int o = 0; o < CB; o++) {
    for (int dbase = 0; dbase < D_IN; dbase += 256) {
      int d = dbase + tid;
      if (d < D_IN) {
        float f = w[o * D_IN + d];
        unsigned short h1 = bf16rn(f);
        float r1 = f - bf16tof(h1);
        unsigned short h2 = bf16rn(r1);
        float r2 = r1 - bf16tof(h2);
        unsigned short h3 = bf16rn(r2);
        int c = d >> 5, qq = (d >> 3) & 3, pos = d & 7;
        int ln = qq * 16 + o;
        wfrag[0][c][ln][pos] = (short)h1;
        wfrag[1][c][ln][pos] = (short)h2;
        wfrag[2][c][ln][pos] = (short)h3;
      }
    }
  }

  const float* xblk = x + (size_t)bid * 64 * D_IN;
  {
    int row = tid >> 2, k0 = (tid & 3) * 8;
    float4 v0 = *(const float4*)(xblk + row * D_IN + k0);
    float4 v1 = *(const float4*)(xblk + row * D_IN + k0 + 4);
    *(float4*)&xs[0][row * 36 + k0] = v0;
    *(float4*)&xs[0][row * 36 + k0 + 4] = v1;
  }
  __syncthreads();

  const int m = lane & 15, q = lane >> 4;
  double dacc[4] = {0.0, 0.0, 0.0, 0.0};
  for (int c = 0; c < 10; c++) {
    const int buf = c & 1;
    if (c < 9) {
      int row = tid >> 2, k0 = (tid & 3) * 8;
      float4 v0 = *(const float4*)(xblk + row * D_IN + (c + 1) * 32 + k0);
      float4 v1 = *(const float4*)(xblk + row * D_IN + (c + 1) * 32 + k0 + 4);
      *(float4*)&xs[buf ^ 1][row * 36 + k0] = v0;
      *(float4*)&xs[buf ^ 1][row * 36 + k0 + 4] = v1;
    }
    const float* xp = &xs[buf][(wv * 16 + m) * 36 + q * 8];
    float4 xa = *(const float4*)xp;
    float4 xb = *(const float4*)(xp + 4);
    float xe[8] = {xa.x, xa.y, xa.z, xa.w, xb.x, xb.y, xb.z, xb.w};
    bf16x8 a1, a2, a3;
#pragma unroll
    for (int j = 0; j < 8; j++) {
      unsigned short h1 = bf16rn(xe[j]);
      float r1 = xe[j] - bf16tof(h1);
      unsigned short h2 = bf16rn(r1);
      float r2 = r1 - bf16tof(h2);
      unsigned short h3 = bf16rn(r2);
      a1[j] = (short)h1; a2[j] = (short)h2; a3[j] = (short)h3;
    }
    bf16x8 b1 = *(const bf16x8*)wfrag[0][c][lane];
    bf16x8 b2 = *(const bf16x8*)wfrag[1][c][lane];
    bf16x8 b3 = *(const bf16x8*)wfrag[2][c][lane];
    f32x4 g = {0.f, 0.f, 0.f, 0.f};
    g = MFMA(a1, b1, g, 0, 0, 0);
#pragma unroll
    for (int r = 0; r < 4; r++) dacc[r] += (double)g[r];
    g = (f32x4){0.f, 0.f, 0.f, 0.f};
    g = MFMA(a2, b1, g, 0, 0, 0);
    g = MFMA(a1, b2, g, 0, 0, 0);
#pragma unroll
    for (int r = 0; r < 4; r++) dacc[r] += (double)g[r];
    g = (f32x4){0.f, 0.f, 0.f, 0.f};
    g = MFMA(a3, b1, g, 0, 0, 0);
    g = MFMA(a1, b3, g, 0, 0, 0);
    g = MFMA(a2, b2, g, 0, 0, 0);
#pragma unroll
    for (int r = 0; r < 4; r++) dacc[r] += (double)g[r];
    __syncthreads();
  }

  float* tl = (float*)xs;  // 64 rows x stride 17
#pragma unroll
  for (int r = 0; r < 4; r++) tl[(wv * 16 + q * 4 + r) * 17 + m] = (float)dacc[r];
  __syncthreads();
  {
    int row_l = tid >> 2, p = tid & 3;
    short h1[4], h2[4];
    float ss = 0.f;
#pragma unroll
    for (int i = 0; i < 4; i++) {
      float f = tl[row_l * 17 + p * 4 + i];
      ss = fmaf(f, f, ss);
      unsigned short a = bf16rn(f);
      float r1 = f - bf16tof(a);
      unsigned short b = bf16rn(r1);
      h1[i] = (short)a; h2[i] = (short)b;
    }
    size_t base = (size_t)(bid * 64 + row_l) * 32;
    *(short4*)(tsplit + base + p * 4) = make_short4(h1[0], h1[1], h1[2], h1[3]);
    *(short4*)(tsplit + base + 16 + p * 4) = make_short4(h2[0], h2[1], h2[2], h2[3]);
    // block-reduce max ||t||^2 -> one atomic per block
    ss += __shfl_xor(ss, 1);
    ss += __shfl_xor(ss, 2);  // quad sum = row T^2
#pragma unroll
    for (int msk = 4; msk <= 32; msk <<= 1) ss = fmaxf(ss, __shfl_xor(ss, msk));
    if (lane == 0) wred[wv] = ss;
  }
  __syncthreads();
  if (tid == 0)
    atomicMaxPosF(gmaxT2, fmaxf(fmaxf(wred[0], wred[1]), fmaxf(wred[2], wred[3])));
}

// ================= Kernel B: scores + fused top-2 argmax =================
// grid = 128 row-groups x 16 chunks (512 books) = 2048 blocks. Block: 256 rows.
// Chunk = 32 bt x 512 shorts = 16384 shorts. Substage = 4 bt (4 KB) double-buffered
// via 1 global_load_lds per wave. 2 MFMA/tile: (t1+t2).(c1+c2).
#define SC_NCH 16

__global__ __launch_bounds__(256, 5) void score_kernel(const short* __restrict__ tsplit,
                                                       const short* __restrict__ bfrag,
                                                       const float* __restrict__ nh_g,
                                                       float* __restrict__ cs1,
                                                       float* __restrict__ cs2,
                                                       int* __restrict__ cidx) {
  __shared__ __align__(16) short ldsb[2][2048];  // 2 x 4 KB
  __shared__ float ldsnh[512];                   // 2 KB
  const int tid = threadIdx.x;
  const int lane = tid & 63;
  const int wv = tid >> 6;
  const int m = lane & 15, q = lane >> 4;
  const int rb = blockIdx.x & 127;
  const int ch = blockIdx.x >> 7;
  const int rowbase = rb * 256;

  bf16x8 A12[4];
#pragma unroll
  for (int rt = 0; rt < 4; rt++) {
    int row = rowbase + wv * 64 + rt * 16 + m;
    A12[rt] = *(const bf16x8*)(tsplit + (size_t)row * 32 + (q & 1) * 8 + ((q >= 2) ? 16 : 0));
  }
  for (int i = tid; i < 512; i += 256) ldsnh[i] = nh_g[ch * 512 + i];

  const short* gq = bfrag + (size_t)ch * 16384;  // 32 bt x 512 shorts per chunk
  gload_lds16(gq + wv * 512 + lane * 8, &ldsb[0][wv * 512]);

  float s1[4][4], s2[4][4];
  int i1[4][4];
#pragma unroll
  for (int rt = 0; rt < 4; rt++)
#pragma unroll
    for (int r = 0; r < 4; r++) { s1[rt][r] = -3.4e38f; s2[rt][r] = -3.4e38f; i1[rt][r] = 0; }

  __syncthreads();  // drains substage-0 gload + nh writes

  for (int sc = 0; sc < 8; sc++) {
    const int cur = sc & 1;
    if (sc < 7)
      gload_lds16(gq + (sc + 1) * 2048 + wv * 512 + lane * 8, &ldsb[cur ^ 1][wv * 512]);
#pragma unroll
    for (int bt = 0; bt < 4; bt++) {
      const short* bp = &ldsb[cur][bt * 512];
      const int l31 = (lane & 31) * 8;
      bf16x8 b1 = *(const bf16x8*)(bp + l31);        // [c1|c1] via broadcast
      bf16x8 b2 = *(const bf16x8*)(bp + 256 + l31);  // [c2|c2]
      const int btg = sc * 4 + bt;
      float nh0 = ldsnh[btg * 16 + m];
      f32x4 ci = {nh0, nh0, nh0, nh0};
      const int colv = ch * 512 + btg * 16 + m;
#pragma unroll
      for (int rt = 0; rt < 4; rt++) {
        f32x4 acc = MFMA(A12[rt], b1, ci, 0, 0, 0);
        acc = MFMA(A12[rt], b2, acc, 0, 0, 0);  // (t1+t2).(c1+c2)
#pragma unroll
        for (int r = 0; r < 4; r++) {
          float v = acc[r];
          float s1o = s1[rt][r];
          s2[rt][r] = __builtin_amdgcn_fmed3f(v, s1o, s2[rt][r]);
          s1[rt][r] = fmaxf(s1o, v);
          i1[rt][r] = (v > s1o) ? colv : i1[rt][r];  // strict: earlier bt wins ties
        }
      }
    }
    __syncthreads();
  }

  // cross-lane top-2 merge over 16 column-lanes (ties -> min index)
#pragma unroll
  for (int rt = 0; rt < 4; rt++)
#pragma unroll
    for (int r = 0; r < 4; r++) {
      float a1v = s1[rt][r], a2v = s2[rt][r];
      int ai = i1[rt][r];
#pragma unroll
      for (int msk = 1; msk <= 8; msk <<= 1) {
        float o1 = __shfl_xor(a1v, msk);
        float o2 = __shfl_xor(a2v, msk);
        int oi = __shfl_xor(ai, msk);
        if (o1 > a1v) {
          a2v = fmaxf(a1v, o2); a1v = o1; ai = oi;
        } else {
          a2v = fmaxf(a2v, o1);
          if (o1 == a1v && oi < ai) ai = oi;
        }
      }
      if (m == 0) {
        int row = rowbase + wv * 64 + rt * 16 + q * 4 + r;
        size_t idx = (size_t)ch * N_ROWS + row;
        cs1[idx] = a1v; cs2[idx] = a2v; cidx[idx] = ai;
      }
    }
}

// ================= Kernel C: merge chunks; label + compact flagged-row list ==========
// Rigorous data-dependent margin: score error E <= 2^-16.4*T*C + 2^-19*C^2 per book;
// a wrong unflagged label requires gap >= 2E. margin = 2^-13*maxT*maxC + 1e-4 >= 5x that.
__global__ __launch_bounds__(256) void reduce_kernel(const float* __restrict__ cs1,
                                                     const float* __restrict__ cs2,
                                                     const int* __restrict__ cidx,
                                                     const int* __restrict__ gmaxT2,
                                                     const int* __restrict__ gmaxC2,
                                                     int* __restrict__ out,
                                                     int* __restrict__ list,
                                                     int* __restrict__ nflag) {
  const int r = blockIdx.x * 256 + threadIdx.x;
  const float margin =
      1.220703125e-4f * sqrtf(__int_as_float(*gmaxT2) * __int_as_float(*gmaxC2)) + 1.0e-4f;
  float S1 = -3.4e38f, S2 = -3.4e38f;
  int I = 0;
#pragma unroll
  for (int ch = 0; ch < SC_NCH; ch++) {  // ascending + strict '>' => min index on ties
    size_t idx = (size_t)ch * N_ROWS + r;
    float v1 = cs1[idx], v2 = cs2[idx];
    if (v1 > S1) {
      S2 = fmaxf(S1, v2); S1 = v1; I = cidx[idx];
    } else {
      S2 = fmaxf(S2, v1);
    }
  }
  out[r] = I;
  if (S1 - S2 < margin) {
    int slot = atomicAdd(nflag, 1);
    list[slot] = r;
  }
}

// ================= Kernel D: exact fp64 rescore of listed rows (grid-parallel) ========
__global__ __launch_bounds__(256) void fb_kernel(const int* __restrict__ list,
                                                 const int* __restrict__ nflag,
                                                 const float* __restrict__ x,
                                                 const float* __restrict__ w,
                                                 const float* __restrict__ codebook,
                                                 int* __restrict__ out) {
  __shared__ double ps[16][17];
  __shared__ double tsh[16];
  __shared__ double rs[256];
  __shared__ int ri[256];
  const int tid = threadIdx.x;
  const int cnt = *nflag;
  for (int i = blockIdx.x; i < cnt; i += gridDim.x) {
    const int row = list[i];
    {  // exact fp64 t = x_row . W^T
      int o = tid & 15, c = tid >> 4;
      double p = 0.0;
      for (int k = 0; k < 20; k++) {
        int d = c * 20 + k;
        p = fma((double)x[(size_t)row * D_IN + d], (double)w[o * D_IN + d], p);
      }
      ps[c][o] = p;
    }
    __syncthreads();
    if (tid < 16) {
      double t = 0.0;
      for (int c = 0; c < 16; c++) t += ps[c][tid];
      tsh[tid] = t;
    }
    __syncthreads();
    double t[16];
#pragma unroll
    for (int k = 0; k < 16; k++) t[k] = tsh[k];
    double bs = -1.0e300;
    int bi = 0;
    for (int j = tid; j < N_BOOKS; j += 256) {
      const float* cp = codebook + (size_t)j * CB;
      double dot = 0.0, cc = 0.0;
#pragma unroll
      for (int k = 0; k < 16; k++) {
        double cv = (double)cp[k];
        dot = fma(t[k], cv, dot);
        cc = fma(cv, cv, cc);
      }
      double mv = dot - 0.5 * cc;
      if (mv > bs) { bs = mv; bi = j; }  // ascending j: first wins
    }
    rs[tid] = bs; ri[tid] = bi;
    __syncthreads();
    for (int s = 128; s > 0; s >>= 1) {
      if (tid < s) {
        double os = rs[tid + s]; int oi = ri[tid + s];
        if (os > rs[tid] || (os == rs[tid] && oi < ri[tid])) { rs[tid] = os; ri[tid] = oi; }
      }
      __syncthreads();
    }
    if (tid == 0) out[row] = ri[0];
    __syncthreads();
  }
}

extern "C" void kernel_launch(void* const* d_in, const int* in_sizes, int n_in,
                              void* d_out, int out_size, void* d_ws, size_t ws_size,
                              hipStream_t stream) {
  (void)in_sizes; (void)n_in; (void)out_size; (void)ws_size;
  const float* x = (const float*)d_in[0];
  // d_in[1] = mask_time_indices: all-ones -> flatten; unused
  const float* w = (const float*)d_in[2];
  const float* codebook = (const float*)d_in[3];

  char* ws = (char*)d_ws;
  short* tsplit = (short*)(ws);               // 2 MB   @0
  short* bfrag = (short*)(ws + (2 << 20));    // 512 KB @2M
  float* nh_g = (float*)(ws + 2621440);       // 32 KB  @2.5M
  float* cs1 = (float*)(ws + (3 << 20));      // 2 MB   @3M
  float* cs2 = (float*)(ws + (5 << 20));      // 2 MB   @5M
  int* cidx = (int*)(ws + (7 << 20));         // 2 MB   @7M
  int* list = (int*)(ws + (9 << 20));         // 128 KB @9M
  int* scalars = (int*)(ws + (9 << 20) + (128 << 10));  // nflag, gmaxT2, gmaxC2
  int* nflag = scalars;
  int* gmaxT2 = scalars + 1;
  int* gmaxC2 = scalars + 2;
  int* out = (int*)d_out;

  hipMemsetAsync(scalars, 0, 3 * sizeof(int), stream);
  prep_proj_kernel<<<32 + N_ROWS / 64, 256, 0, stream>>>(codebook, x, w, bfrag, nh_g, tsplit,
                                                         gmaxT2, gmaxC2);
  score_kernel<<<128 * SC_NCH, 256, 0, stream>>>(tsplit, bfrag, nh_g, cs1, cs2, cidx);
  reduce_kernel<<<N_ROWS / 256, 256, 0, stream>>>(cs1, cs2, cidx, gmaxT2, gmaxC2, out, list, nflag);
  fb_kernel<<<64, 256, 0, stream>>>(list, nflag, x, w, codebook, out);
}

// Round 10
// 253.414 us; speedup vs baseline: 1.2429x; 1.2429x over previous
//
#include <hip/hip_runtime.h>

#define N_ROWS 32768
#define D_IN 320
#define CB 16
#define N_BOOKS 8192

typedef __attribute__((ext_vector_type(8))) short bf16x8;
typedef __attribute__((ext_vector_type(4))) float f32x4;
#define MFMA __builtin_amdgcn_mfma_f32_16x16x32_bf16
#define AS1 __attribute__((address_space(1)))
#define AS3 __attribute__((address_space(3)))

__device__ __forceinline__ unsigned short bf16rn(float f) {
  unsigned u = __float_as_uint(f);
  u += 0x7fffu + ((u >> 16) & 1u);
  return (unsigned short)(u >> 16);
}
__device__ __forceinline__ float bf16tof(unsigned short h) {
  return __uint_as_float(((unsigned)h) << 16);
}
__device__ __forceinline__ void gload_lds16(const short* g, short* l) {
  __builtin_amdgcn_global_load_lds((const AS1 unsigned int*)g, (AS3 unsigned int*)l, 16, 0, 0);
}
// atomic max for non-negative floats via int-bit ordering
__device__ __forceinline__ void atomicMaxPosF(int* addr, float v) {
  atomicMax(addr, __float_as_int(v));
}

// ================= Kernel A: fused prep (codebook 2-split frag-pack) + proj =================
// blocks 0..31: prep. Per 16-book tile bt: 512 shorts = lo1|hi1 (B1 dedup) + lo2|hi2 (B2 dedup).
// MFMA B-frag upper 32 lanes duplicate lower 32 -> read with (lane&31): free 2-way broadcast.
// Also atomicMax of ||c||^2 into gmaxC2.
// blocks 32..543: proj = X @ W^T via bf16 3-split MFMA, fp64 flush; writes
//   tsplit[row][32] = t1[16]|t2[16]; atomicMax of ||t||^2 into gmaxT2.
__global__ __launch_bounds__(256, 2) void prep_proj_kernel(const float* __restrict__ cbk,
                                                           const float* __restrict__ x,
                                                           const float* __restrict__ w,
                                                           short* __restrict__ bfrag,
                                                           float* __restrict__ nh_g,
                                                           short* __restrict__ tsplit,
                                                           int* __restrict__ gmaxT2,
                                                           int* __restrict__ gmaxC2) {
  __shared__ __align__(16) short wfrag[3][10][64][8];  // 30720 B
  __shared__ __align__(16) float xs[2][64 * 36];       // 18432 B
  __shared__ float wred[4];
  const int tid = threadIdx.x;

  if (blockIdx.x < 32) {  // ---------- prep ----------
    const int j = blockIdx.x * 256 + tid;
    const float4* src = (const float4*)(cbk + (size_t)j * CB);
    float4 a = src[0], b = src[1], c = src[2], d = src[3];
    float ce[16] = {a.x, a.y, a.z, a.w, b.x, b.y, b.z, b.w,
                    c.x, c.y, c.z, c.w, d.x, d.y, d.z, d.w};
    short c1[16], c2[16];
    double s = 0.0;
#pragma unroll
    for (int i = 0; i < 16; i++) {
      s += (double)ce[i] * (double)ce[i];
      unsigned short x1 = bf16rn(ce[i]);
      float r1 = ce[i] - bf16tof(x1);
      unsigned short x2 = bf16rn(r1);
      c1[i] = (short)x1; c2[i] = (short)x2;
    }
    nh_g[j] = (float)(-0.5 * s);
    bf16x8 lo1, hi1, lo2, hi2;
#pragma unroll
    for (int i = 0; i < 8; i++) {
      lo1[i] = c1[i]; hi1[i] = c1[i + 8];
      lo2[i] = c2[i]; hi2[i] = c2[i + 8];
    }
    short* base = bfrag + (size_t)(j >> 4) * 512;
    const int n = j & 15;
    *(bf16x8*)(base + 0 + n * 8) = lo1;
    *(bf16x8*)(base + 128 + n * 8) = hi1;
    *(bf16x8*)(base + 256 + n * 8) = lo2;
    *(bf16x8*)(base + 384 + n * 8) = hi2;
    // block-reduce max ||c||^2 -> one atomic per block
    float c2f = (float)s;
#pragma unroll
    for (int msk = 1; msk <= 32; msk <<= 1) c2f = fmaxf(c2f, __shfl_xor(c2f, msk));
    if ((tid & 63) == 0) wred[tid >> 6] = c2f;
    __syncthreads();
    if (tid == 0)
      atomicMaxPosF(gmaxC2, fmaxf(fmaxf(wred[0], wred[1]), fmaxf(wred[2], wred[3])));
    return;
  }

  // ---------- proj ----------
  const int bid = blockIdx.x - 32;
  const int lane = tid & 63;
  const int wv = tid >> 6;

  for (int o = 0; o < CB; o++) {
    for (int dbase = 0; dbase < D_IN; dbase += 256) {
      int d = dbase + tid;
      if (d < D_IN) {
        float f = w[o * D_IN + d];
        unsigned short h1 = bf16rn(f);
        float r1 = f - bf16tof(h1);
        unsigned short h2 = bf16rn(r1);
        float r2 = r1 - bf16tof(h2);
        unsigned short h3 = bf16rn(r2);
        int c = d >> 5, qq = (d >> 3) & 3, pos = d & 7;
        int ln = qq * 16 + o;
        wfrag[0][c][ln][pos] = (short)h1;
        wfrag[1][c][ln][pos] = (short)h2;
        wfrag[2][c][ln][pos] = (short)h3;
      }
    }
  }

  const float* xblk = x + (size_t)bid * 64 * D_IN;
  {
    int row = tid >> 2, k0 = (tid & 3) * 8;
    float4 v0 = *(const float4*)(xblk + row * D_IN + k0);
    float4 v1 = *(const float4*)(xblk + row * D_IN + k0 + 4);
    *(float4*)&xs[0][row * 36 + k0] = v0;
    *(float4*)&xs[0][row * 36 + k0 + 4] = v1;
  }
  __syncthreads();

  const int m = lane & 15, q = lane >> 4;
  double dacc[4] = {0.0, 0.0, 0.0, 0.0};
  for (int c = 0; c < 10; c++) {
    const int buf = c & 1;
    if (c < 9) {
      int row = tid >> 2, k0 = (tid & 3) * 8;
      float4 v0 = *(const float4*)(xblk + row * D_IN + (c + 1) * 32 + k0);
      float4 v1 = *(const float4*)(xblk + row * D_IN + (c + 1) * 32 + k0 + 4);
      *(float4*)&xs[buf ^ 1][row * 36 + k0] = v0;
      *(float4*)&xs[buf ^ 1][row * 36 + k0 + 4] = v1;
    }
    const float* xp = &xs[buf][(wv * 16 + m) * 36 + q * 8];
    float4 xa = *(const float4*)xp;
    float4 xb = *(const float4*)(xp + 4);
    float xe[8] = {xa.x, xa.y, xa.z, xa.w, xb.x, xb.y, xb.z, xb.w};
    bf16x8 a1, a2, a3;
#pragma unroll
    for (int j = 0; j < 8; j++) {
      unsigned short h1 = bf16rn(xe[j]);
      float r1 = xe[j] - bf16tof(h1);
      unsigned short h2 = bf16rn(r1);
      float r2 = r1 - bf16tof(h2);
      unsigned short h3 = bf16rn(r2);
      a1[j] = (short)h1; a2[j] = (short)h2; a3[j] = (short)h3;
    }
    bf16x8 b1 = *(const bf16x8*)wfrag[0][c][lane];
    bf16x8 b2 = *(const bf16x8*)wfrag[1][c][lane];
    bf16x8 b3 = *(const bf16x8*)wfrag[2][c][lane];
    f32x4 g = {0.f, 0.f, 0.f, 0.f};
    g = MFMA(a1, b1, g, 0, 0, 0);
#pragma unroll
    for (int r = 0; r < 4; r++) dacc[r] += (double)g[r];
    g = (f32x4){0.f, 0.f, 0.f, 0.f};
    g = MFMA(a2, b1, g, 0, 0, 0);
    g = MFMA(a1, b2, g, 0, 0, 0);
#pragma unroll
    for (int r = 0; r < 4; r++) dacc[r] += (double)g[r];
    g = (f32x4){0.f, 0.f, 0.f, 0.f};
    g = MFMA(a3, b1, g, 0, 0, 0);
    g = MFMA(a1, b3, g, 0, 0, 0);
    g = MFMA(a2, b2, g, 0, 0, 0);
#pragma unroll
    for (int r = 0; r < 4; r++) dacc[r] += (double)g[r];
    __syncthreads();
  }

  float* tl = (float*)xs;  // 64 rows x stride 17
#pragma unroll
  for (int r = 0; r < 4; r++) tl[(wv * 16 + q * 4 + r) * 17 + m] = (float)dacc[r];
  __syncthreads();
  {
    int row_l = tid >> 2, p = tid & 3;
    short h1[4], h2[4];
    float ss = 0.f;
#pragma unroll
    for (int i = 0; i < 4; i++) {
      float f = tl[row_l * 17 + p * 4 + i];
      ss = fmaf(f, f, ss);
      unsigned short a = bf16rn(f);
      float r1 = f - bf16tof(a);
      unsigned short b = bf16rn(r1);
      h1[i] = (short)a; h2[i] = (short)b;
    }
    size_t base = (size_t)(bid * 64 + row_l) * 32;
    *(short4*)(tsplit + base + p * 4) = make_short4(h1[0], h1[1], h1[2], h1[3]);
    *(short4*)(tsplit + base + 16 + p * 4) = make_short4(h2[0], h2[1], h2[2], h2[3]);
    // block-reduce max ||t||^2 -> one atomic per block
    ss += __shfl_xor(ss, 1);
    ss += __shfl_xor(ss, 2);  // quad sum = row T^2
#pragma unroll
    for (int msk = 4; msk <= 32; msk <<= 1) ss = fmaxf(ss, __shfl_xor(ss, msk));
    if (lane == 0) wred[wv] = ss;
  }
  __syncthreads();
  if (tid == 0)
    atomicMaxPosF(gmaxT2, fmaxf(fmaxf(wred[0], wred[1]), fmaxf(wred[2], wred[3])));
}

// ================= Kernel B: scores + fused top-2 argmax =================
// grid = 128 row-groups x 16 chunks (512 books) = 2048 blocks. Block: 256 rows.
// Chunk = 32 bt x 512 shorts = 16384 shorts. Substage = 4 bt (4 KB) double-buffered
// via 1 global_load_lds per wave. 2 MFMA/tile: (t1+t2).(c1+c2).
// launch_bounds (256,4): (256,5) starved the unified VGPR/AGPR budget -> scratch
// spill (R9: VGPR 48, WRITE_SIZE 210 MB). (256,4) fits the state (R7: VGPR 64, no spill).
#define SC_NCH 16

__global__ __launch_bounds__(256, 4) void score_kernel(const short* __restrict__ tsplit,
                                                       const short* __restrict__ bfrag,
                                                       const float* __restrict__ nh_g,
                                                       float* __restrict__ cs1,
                                                       float* __restrict__ cs2,
                                                       int* __restrict__ cidx) {
  __shared__ __align__(16) short ldsb[2][2048];  // 2 x 4 KB
  __shared__ float ldsnh[512];                   // 2 KB
  const int tid = threadIdx.x;
  const int lane = tid & 63;
  const int wv = tid >> 6;
  const int m = lane & 15, q = lane >> 4;
  const int rb = blockIdx.x & 127;
  const int ch = blockIdx.x >> 7;
  const int rowbase = rb * 256;

  bf16x8 A12[4];
#pragma unroll
  for (int rt = 0; rt < 4; rt++) {
    int row = rowbase + wv * 64 + rt * 16 + m;
    A12[rt] = *(const bf16x8*)(tsplit + (size_t)row * 32 + (q & 1) * 8 + ((q >= 2) ? 16 : 0));
  }
  for (int i = tid; i < 512; i += 256) ldsnh[i] = nh_g[ch * 512 + i];

  const short* gq = bfrag + (size_t)ch * 16384;  // 32 bt x 512 shorts per chunk
  gload_lds16(gq + wv * 512 + lane * 8, &ldsb[0][wv * 512]);

  float s1[4][4], s2[4][4];
  int i1[4][4];
#pragma unroll
  for (int rt = 0; rt < 4; rt++)
#pragma unroll
    for (int r = 0; r < 4; r++) { s1[rt][r] = -3.4e38f; s2[rt][r] = -3.4e38f; i1[rt][r] = 0; }

  __syncthreads();  // drains substage-0 gload + nh writes

  for (int sc = 0; sc < 8; sc++) {
    const int cur = sc & 1;
    if (sc < 7)
      gload_lds16(gq + (sc + 1) * 2048 + wv * 512 + lane * 8, &ldsb[cur ^ 1][wv * 512]);
#pragma unroll
    for (int bt = 0; bt < 4; bt++) {
      const short* bp = &ldsb[cur][bt * 512];
      const int l31 = (lane & 31) * 8;
      bf16x8 b1 = *(const bf16x8*)(bp + l31);        // [c1|c1] via broadcast
      bf16x8 b2 = *(const bf16x8*)(bp + 256 + l31);  // [c2|c2]
      const int btg = sc * 4 + bt;
      float nh0 = ldsnh[btg * 16 + m];
      f32x4 ci = {nh0, nh0, nh0, nh0};
      const int colv = ch * 512 + btg * 16 + m;
#pragma unroll
      for (int rt = 0; rt < 4; rt++) {
        f32x4 acc = MFMA(A12[rt], b1, ci, 0, 0, 0);
        acc = MFMA(A12[rt], b2, acc, 0, 0, 0);  // (t1+t2).(c1+c2)
#pragma unroll
        for (int r = 0; r < 4; r++) {
          float v = acc[r];
          float s1o = s1[rt][r];
          s2[rt][r] = __builtin_amdgcn_fmed3f(v, s1o, s2[rt][r]);
          s1[rt][r] = fmaxf(s1o, v);
          i1[rt][r] = (v > s1o) ? colv : i1[rt][r];  // strict: earlier bt wins ties
        }
      }
    }
    __syncthreads();
  }

  // cross-lane top-2 merge over 16 column-lanes (ties -> min index)
#pragma unroll
  for (int rt = 0; rt < 4; rt++)
#pragma unroll
    for (int r = 0; r < 4; r++) {
      float a1v = s1[rt][r], a2v = s2[rt][r];
      int ai = i1[rt][r];
#pragma unroll
      for (int msk = 1; msk <= 8; msk <<= 1) {
        float o1 = __shfl_xor(a1v, msk);
        float o2 = __shfl_xor(a2v, msk);
        int oi = __shfl_xor(ai, msk);
        if (o1 > a1v) {
          a2v = fmaxf(a1v, o2); a1v = o1; ai = oi;
        } else {
          a2v = fmaxf(a2v, o1);
          if (o1 == a1v && oi < ai) ai = oi;
        }
      }
      if (m == 0) {
        int row = rowbase + wv * 64 + rt * 16 + q * 4 + r;
        size_t idx = (size_t)ch * N_ROWS + row;
        cs1[idx] = a1v; cs2[idx] = a2v; cidx[idx] = ai;
      }
    }
}

// ================= Kernel C: merge chunks; label + compact flagged-row list ==========
// Rigorous data-dependent margin: score error E <= 2^-16.4*T*C + 2^-19*C^2 per book;
// a wrong unflagged label requires gap >= 2E. margin = 2^-13*maxT*maxC + 1e-4 >= 5x that.
__global__ __launch_bounds__(256) void reduce_kernel(const float* __restrict__ cs1,
                                                     const float* __restrict__ cs2,
                                                     const int* __restrict__ cidx,
                                                     const int* __restrict__ gmaxT2,
                                                     const int* __restrict__ gmaxC2,
                                                     int* __restrict__ out,
                                                     int* __restrict__ list,
                                                     int* __restrict__ nflag) {
  const int r = blockIdx.x * 256 + threadIdx.x;
  const float margin =
      1.220703125e-4f * sqrtf(__int_as_float(*gmaxT2) * __int_as_float(*gmaxC2)) + 1.0e-4f;
  float S1 = -3.4e38f, S2 = -3.4e38f;
  int I = 0;
#pragma unroll
  for (int ch = 0; ch < SC_NCH; ch++) {  // ascending + strict '>' => min index on ties
    size_t idx = (size_t)ch * N_ROWS + r;
    float v1 = cs1[idx], v2 = cs2[idx];
    if (v1 > S1) {
      S2 = fmaxf(S1, v2); S1 = v1; I = cidx[idx];
    } else {
      S2 = fmaxf(S2, v1);
    }
  }
  out[r] = I;
  if (S1 - S2 < margin) {
    int slot = atomicAdd(nflag, 1);
    list[slot] = r;
  }
}

// ================= Kernel D: exact fp64 rescore of listed rows (grid-parallel) ========
__global__ __launch_bounds__(256) void fb_kernel(const int* __restrict__ list,
                                                 const int* __restrict__ nflag,
                                                 const float* __restrict__ x,
                                                 const float* __restrict__ w,
                                                 const float* __restrict__ codebook,
                                                 int* __restrict__ out) {
  __shared__ double ps[16][17];
  __shared__ double tsh[16];
  __shared__ double rs[256];
  __shared__ int ri[256];
  const int tid = threadIdx.x;
  const int cnt = *nflag;
  for (int i = blockIdx.x; i < cnt; i += gridDim.x) {
    const int row = list[i];
    {  // exact fp64 t = x_row . W^T
      int o = tid & 15, c = tid >> 4;
      double p = 0.0;
      for (int k = 0; k < 20; k++) {
        int d = c * 20 + k;
        p = fma((double)x[(size_t)row * D_IN + d], (double)w[o * D_IN + d], p);
      }
      ps[c][o] = p;
    }
    __syncthreads();
    if (tid < 16) {
      double t = 0.0;
      for (int c = 0; c < 16; c++) t += ps[c][tid];
      tsh[tid] = t;
    }
    __syncthreads();
    double t[16];
#pragma unroll
    for (int k = 0; k < 16; k++) t[k] = tsh[k];
    double bs = -1.0e300;
    int bi = 0;
    for (int j = tid; j < N_BOOKS; j += 256) {
      const float* cp = codebook + (size_t)j * CB;
      double dot = 0.0, cc = 0.0;
#pragma unroll
      for (int k = 0; k < 16; k++) {
        double cv = (double)cp[k];
        dot = fma(t[k], cv, dot);
        cc = fma(cv, cv, cc);
      }
      double mv = dot - 0.5 * cc;
      if (mv > bs) { bs = mv; bi = j; }  // ascending j: first wins
    }
    rs[tid] = bs; ri[tid] = bi;
    __syncthreads();
    for (int s = 128; s > 0; s >>= 1) {
      if (tid < s) {
        double os = rs[tid + s]; int oi = ri[tid + s];
        if (os > rs[tid] || (os == rs[tid] && oi < ri[tid])) { rs[tid] = os; ri[tid] = oi; }
      }
      __syncthreads();
    }
    if (tid == 0) out[row] = ri[0];
    __syncthreads();
  }
}

extern "C" void kernel_launch(void* const* d_in, const int* in_sizes, int n_in,
                              void* d_out, int out_size, void* d_ws, size_t ws_size,
                              hipStream_t stream) {
  (void)in_sizes; (void)n_in; (void)out_size; (void)ws_size;
  const float* x = (const float*)d_in[0];
  // d_in[1] = mask_time_indices: all-ones -> flatten; unused
  const float* w = (const float*)d_in[2];
  const float* codebook = (const float*)d_in[3];

  char* ws = (char*)d_ws;
  short* tsplit = (short*)(ws);               // 2 MB   @0
  short* bfrag = (short*)(ws + (2 << 20));    // 512 KB @2M
  float* nh_g = (float*)(ws + 2621440);       // 32 KB  @2.5M
  float* cs1 = (float*)(ws + (3 << 20));      // 2 MB   @3M
  float* cs2 = (float*)(ws + (5 << 20));      // 2 MB   @5M
  int* cidx = (int*)(ws + (7 << 20));         // 2 MB   @7M
  int* list = (int*)(ws + (9 << 20));         // 128 KB @9M
  int* scalars = (int*)(ws + (9 << 20) + (128 << 10));  // nflag, gmaxT2, gmaxC2
  int* nflag = scalars;
  int* gmaxT2 = scalars + 1;
  int* gmaxC2 = scalars + 2;
  int* out = (int*)d_out;

  hipMemsetAsync(scalars, 0, 3 * sizeof(int), stream);
  prep_proj_kernel<<<32 + N_ROWS / 64, 256, 0, stream>>>(codebook, x, w, bfrag, nh_g, tsplit,
                                                         gmaxT2, gmaxC2);
  score_kernel<<<128 * SC_NCH, 256, 0, stream>>>(tsplit, bfrag, nh_g, cs1, cs2, cidx);
  reduce_kernel<<<N_ROWS / 256, 256, 0, stream>>>(cs1, cs2, cidx, gmaxT2, gmaxC2, out, list, nflag);
  fb_kernel<<<64, 256, 0, stream>>>(list, nflag, x, w, codebook, out);
}

// Round 11
// 242.605 us; speedup vs baseline: 1.2983x; 1.0446x over previous
//
#include <hip/hip_runtime.h>

#define N_ROWS 32768
#define D_IN 320
#define CB 16
#define N_BOOKS 8192

typedef __attribute__((ext_vector_type(8))) short bf16x8;
typedef __attribute__((ext_vector_type(4))) float f32x4;
#define MFMA __builtin_amdgcn_mfma_f32_16x16x32_bf16
#define AS1 __attribute__((address_space(1)))
#define AS3 __attribute__((address_space(3)))

__device__ __forceinline__ unsigned short bf16rn(float f) {
  unsigned u = __float_as_uint(f);
  u += 0x7fffu + ((u >> 16) & 1u);
  return (unsigned short)(u >> 16);
}
__device__ __forceinline__ float bf16tof(unsigned short h) {
  return __uint_as_float(((unsigned)h) << 16);
}
__device__ __forceinline__ void gload_lds16(const short* g, short* l) {
  __builtin_amdgcn_global_load_lds((const AS1 unsigned int*)g, (AS3 unsigned int*)l, 16, 0, 0);
}
// atomic max for non-negative floats via int-bit ordering
__device__ __forceinline__ void atomicMaxPosF(int* addr, float v) {
  atomicMax(addr, __float_as_int(v));
}

// ================= Kernel A: fused prep (codebook 2-split frag-pack) + proj =================
// blocks 0..31: prep. Per 16-book tile bt: 512 shorts = lo1|hi1 (B1 dedup) + lo2|hi2 (B2 dedup).
// MFMA B-frag upper 32 lanes duplicate lower 32 -> read with (lane&31): free 2-way broadcast.
// Also atomicMax of ||c||^2 into gmaxC2.
// blocks 32..543: proj = X @ W^T via bf16 3-split MFMA, fp64 flush; writes
//   tsplit[row][32] = t1[16]|t2[16]; atomicMax of ||t||^2 into gmaxT2.
// launch_bounds (256,3): 49 KB LDS -> 3 blocks/CU, 544 blocks in one residency round.
__global__ __launch_bounds__(256, 3) void prep_proj_kernel(const float* __restrict__ cbk,
                                                           const float* __restrict__ x,
                                                           const float* __restrict__ w,
                                                           short* __restrict__ bfrag,
                                                           float* __restrict__ nh_g,
                                                           short* __restrict__ tsplit,
                                                           int* __restrict__ gmaxT2,
                                                           int* __restrict__ gmaxC2) {
  __shared__ __align__(16) short wfrag[3][10][64][8];  // 30720 B
  __shared__ __align__(16) float xs[2][64 * 36];       // 18432 B
  __shared__ float wred[4];
  const int tid = threadIdx.x;

  if (blockIdx.x < 32) {  // ---------- prep ----------
    const int j = blockIdx.x * 256 + tid;
    const float4* src = (const float4*)(cbk + (size_t)j * CB);
    float4 a = src[0], b = src[1], c = src[2], d = src[3];
    float ce[16] = {a.x, a.y, a.z, a.w, b.x, b.y, b.z, b.w,
                    c.x, c.y, c.z, c.w, d.x, d.y, d.z, d.w};
    short c1[16], c2[16];
    double s = 0.0;
#pragma unroll
    for (int i = 0; i < 16; i++) {
      s += (double)ce[i] * (double)ce[i];
      unsigned short x1 = bf16rn(ce[i]);
      float r1 = ce[i] - bf16tof(x1);
      unsigned short x2 = bf16rn(r1);
      c1[i] = (short)x1; c2[i] = (short)x2;
    }
    nh_g[j] = (float)(-0.5 * s);
    bf16x8 lo1, hi1, lo2, hi2;
#pragma unroll
    for (int i = 0; i < 8; i++) {
      lo1[i] = c1[i]; hi1[i] = c1[i + 8];
      lo2[i] = c2[i]; hi2[i] = c2[i + 8];
    }
    short* base = bfrag + (size_t)(j >> 4) * 512;
    const int n = j & 15;
    *(bf16x8*)(base + 0 + n * 8) = lo1;
    *(bf16x8*)(base + 128 + n * 8) = hi1;
    *(bf16x8*)(base + 256 + n * 8) = lo2;
    *(bf16x8*)(base + 384 + n * 8) = hi2;
    // block-reduce max ||c||^2 -> one atomic per block
    float c2f = (float)s;
#pragma unroll
    for (int msk = 1; msk <= 32; msk <<= 1) c2f = fmaxf(c2f, __shfl_xor(c2f, msk));
    if ((tid & 63) == 0) wred[tid >> 6] = c2f;
    __syncthreads();
    if (tid == 0)
      atomicMaxPosF(gmaxC2, fmaxf(fmaxf(wred[0], wred[1]), fmaxf(wred[2], wred[3])));
    return;
  }

  // ---------- proj ----------
  const int bid = blockIdx.x - 32;
  const int lane = tid & 63;
  const int wv = tid >> 6;

  for (int o = 0; o < CB; o++) {
    for (int dbase = 0; dbase < D_IN; dbase += 256) {
      int d = dbase + tid;
      if (d < D_IN) {
        float f = w[o * D_IN + d];
        unsigned short h1 = bf16rn(f);
        float r1 = f - bf16tof(h1);
        unsigned short h2 = bf16rn(r1);
        float r2 = r1 - bf16tof(h2);
        unsigned short h3 = bf16rn(r2);
        int c = d >> 5, qq = (d >> 3) & 3, pos = d & 7;
        int ln = qq * 16 + o;
        wfrag[0][c][ln][pos] = (short)h1;
        wfrag[1][c][ln][pos] = (short)h2;
        wfrag[2][c][ln][pos] = (short)h3;
      }
    }
  }

  const float* xblk = x + (size_t)bid * 64 * D_IN;
  {
    int row = tid >> 2, k0 = (tid & 3) * 8;
    float4 v0 = *(const float4*)(xblk + row * D_IN + k0);
    float4 v1 = *(const float4*)(xblk + row * D_IN + k0 + 4);
    *(float4*)&xs[0][row * 36 + k0] = v0;
    *(float4*)&xs[0][row * 36 + k0 + 4] = v1;
  }
  __syncthreads();

  const int m = lane & 15, q = lane >> 4;
  double dacc[4] = {0.0, 0.0, 0.0, 0.0};
  for (int c = 0; c < 10; c++) {
    const int buf = c & 1;
    if (c < 9) {
      int row = tid >> 2, k0 = (tid & 3) * 8;
      float4 v0 = *(const float4*)(xblk + row * D_IN + (c + 1) * 32 + k0);
      float4 v1 = *(const float4*)(xblk + row * D_IN + (c + 1) * 32 + k0 + 4);
      *(float4*)&xs[buf ^ 1][row * 36 + k0] = v0;
      *(float4*)&xs[buf ^ 1][row * 36 + k0 + 4] = v1;
    }
    const float* xp = &xs[buf][(wv * 16 + m) * 36 + q * 8];
    float4 xa = *(const float4*)xp;
    float4 xb = *(const float4*)(xp + 4);
    float xe[8] = {xa.x, xa.y, xa.z, xa.w, xb.x, xb.y, xb.z, xb.w};
    bf16x8 a1, a2, a3;
#pragma unroll
    for (int j = 0; j < 8; j++) {
      unsigned short h1 = bf16rn(xe[j]);
      float r1 = xe[j] - bf16tof(h1);
      unsigned short h2 = bf16rn(r1);
      float r2 = r1 - bf16tof(h2);
      unsigned short h3 = bf16rn(r2);
      a1[j] = (short)h1; a2[j] = (short)h2; a3[j] = (short)h3;
    }
    bf16x8 b1 = *(const bf16x8*)wfrag[0][c][lane];
    bf16x8 b2 = *(const bf16x8*)wfrag[1][c][lane];
    bf16x8 b3 = *(const bf16x8*)wfrag[2][c][lane];
    f32x4 g = {0.f, 0.f, 0.f, 0.f};
    g = MFMA(a1, b1, g, 0, 0, 0);
#pragma unroll
    for (int r = 0; r < 4; r++) dacc[r] += (double)g[r];
    g = (f32x4){0.f, 0.f, 0.f, 0.f};
    g = MFMA(a2, b1, g, 0, 0, 0);
    g = MFMA(a1, b2, g, 0, 0, 0);
#pragma unroll
    for (int r = 0; r < 4; r++) dacc[r] += (double)g[r];
    g = (f32x4){0.f, 0.f, 0.f, 0.f};
    g = MFMA(a3, b1, g, 0, 0, 0);
    g = MFMA(a1, b3, g, 0, 0, 0);
    g = MFMA(a2, b2, g, 0, 0, 0);
#pragma unroll
    for (int r = 0; r < 4; r++) dacc[r] += (double)g[r];
    __syncthreads();
  }

  float* tl = (float*)xs;  // 64 rows x stride 17
#pragma unroll
  for (int r = 0; r < 4; r++) tl[(wv * 16 + q * 4 + r) * 17 + m] = (float)dacc[r];
  __syncthreads();
  {
    int row_l = tid >> 2, p = tid & 3;
    short h1[4], h2[4];
    float ss = 0.f;
#pragma unroll
    for (int i = 0; i < 4; i++) {
      float f = tl[row_l * 17 + p * 4 + i];
      ss = fmaf(f, f, ss);
      unsigned short a = bf16rn(f);
      float r1 = f - bf16tof(a);
      unsigned short b = bf16rn(r1);
      h1[i] = (short)a; h2[i] = (short)b;
    }
    size_t base = (size_t)(bid * 64 + row_l) * 32;
    *(short4*)(tsplit + base + p * 4) = make_short4(h1[0], h1[1], h1[2], h1[3]);
    *(short4*)(tsplit + base + 16 + p * 4) = make_short4(h2[0], h2[1], h2[2], h2[3]);
    // block-reduce max ||t||^2 -> one atomic per block
    ss += __shfl_xor(ss, 1);
    ss += __shfl_xor(ss, 2);  // quad sum = row T^2
#pragma unroll
    for (int msk = 4; msk <= 32; msk <<= 1) ss = fmaxf(ss, __shfl_xor(ss, msk));
    if (lane == 0) wred[wv] = ss;
  }
  __syncthreads();
  if (tid == 0)
    atomicMaxPosF(gmaxT2, fmaxf(fmaxf(wred[0], wred[1]), fmaxf(wred[2], wred[3])));
}

// ================= Kernel B: scores + fused top-2 argmax =================
// grid = 128 row-groups x 8 chunks (1024 books) = 1024 blocks = exactly 4 blocks/CU,
// one residency round (16 waves/CU, no tail). Block: 256 rows; 64 bt; substage = 8 bt
// (8 KB) double-buffered via 2 global_load_lds per wave. 2 MFMA/tile: (t1+t2).(c1+c2).
// (256,4): (256,5) starved the unified VGPR budget -> scratch spill (R9). VGPR ~64 here.
#define SC_NCH 8

__global__ __launch_bounds__(256, 4) void score_kernel(const short* __restrict__ tsplit,
                                                       const short* __restrict__ bfrag,
                                                       const float* __restrict__ nh_g,
                                                       float* __restrict__ cs1,
                                                       float* __restrict__ cs2,
                                                       int* __restrict__ cidx) {
  __shared__ __align__(16) short ldsb[2][4096];  // 2 x 8 KB (8 bt x 512 shorts)
  __shared__ float ldsnh[1024];                  // 4 KB
  const int tid = threadIdx.x;
  const int lane = tid & 63;
  const int wv = tid >> 6;
  const int m = lane & 15, q = lane >> 4;
  const int rb = blockIdx.x & 127;
  const int ch = blockIdx.x >> 7;
  const int rowbase = rb * 256;

  bf16x8 A12[4];
#pragma unroll
  for (int rt = 0; rt < 4; rt++) {
    int row = rowbase + wv * 64 + rt * 16 + m;
    A12[rt] = *(const bf16x8*)(tsplit + (size_t)row * 32 + (q & 1) * 8 + ((q >= 2) ? 16 : 0));
  }
  for (int i = tid; i < 1024; i += 256) ldsnh[i] = nh_g[ch * 1024 + i];

  const short* gq = bfrag + (size_t)ch * 32768;  // 64 bt x 512 shorts per chunk
  {  // stage substage 0 (8 bt = 4096 shorts; wave wv covers [wv*1024, wv*1024+1024))
    const short* g0 = gq + wv * 1024 + lane * 8;
    gload_lds16(g0, &ldsb[0][wv * 1024]);
    gload_lds16(g0 + 512, &ldsb[0][wv * 1024 + 512]);
  }

  float s1[4][4], s2[4][4];
  int i1[4][4];
#pragma unroll
  for (int rt = 0; rt < 4; rt++)
#pragma unroll
    for (int r = 0; r < 4; r++) { s1[rt][r] = -3.4e38f; s2[rt][r] = -3.4e38f; i1[rt][r] = 0; }

  __syncthreads();  // drains substage-0 gloads + nh writes

  for (int sc = 0; sc < 8; sc++) {
    const int cur = sc & 1;
    if (sc < 7) {  // async prefetch next substage
      const short* gs = gq + (sc + 1) * 4096 + wv * 1024 + lane * 8;
      gload_lds16(gs, &ldsb[cur ^ 1][wv * 1024]);
      gload_lds16(gs + 512, &ldsb[cur ^ 1][wv * 1024 + 512]);
    }
#pragma unroll
    for (int bt = 0; bt < 8; bt++) {
      const short* bp = &ldsb[cur][bt * 512];
      const int l31 = (lane & 31) * 8;
      bf16x8 b1 = *(const bf16x8*)(bp + l31);        // [c1|c1] via broadcast
      bf16x8 b2 = *(const bf16x8*)(bp + 256 + l31);  // [c2|c2]
      const int btg = sc * 8 + bt;
      float nh0 = ldsnh[btg * 16 + m];
      f32x4 ci = {nh0, nh0, nh0, nh0};
      const int colv = ch * 1024 + btg * 16 + m;
#pragma unroll
      for (int rt = 0; rt < 4; rt++) {
        f32x4 acc = MFMA(A12[rt], b1, ci, 0, 0, 0);
        acc = MFMA(A12[rt], b2, acc, 0, 0, 0);  // (t1+t2).(c1+c2)
#pragma unroll
        for (int r = 0; r < 4; r++) {
          float v = acc[r];
          float s1o = s1[rt][r];
          s2[rt][r] = __builtin_amdgcn_fmed3f(v, s1o, s2[rt][r]);
          s1[rt][r] = fmaxf(s1o, v);
          i1[rt][r] = (v > s1o) ? colv : i1[rt][r];  // strict: earlier bt wins ties
        }
      }
    }
    __syncthreads();
  }

  // cross-lane top-2 merge over 16 column-lanes (ties -> min index)
#pragma unroll
  for (int rt = 0; rt < 4; rt++)
#pragma unroll
    for (int r = 0; r < 4; r++) {
      float a1v = s1[rt][r], a2v = s2[rt][r];
      int ai = i1[rt][r];
#pragma unroll
      for (int msk = 1; msk <= 8; msk <<= 1) {
        float o1 = __shfl_xor(a1v, msk);
        float o2 = __shfl_xor(a2v, msk);
        int oi = __shfl_xor(ai, msk);
        if (o1 > a1v) {
          a2v = fmaxf(a1v, o2); a1v = o1; ai = oi;
        } else {
          a2v = fmaxf(a2v, o1);
          if (o1 == a1v && oi < ai) ai = oi;
        }
      }
      if (m == 0) {
        int row = rowbase + wv * 64 + rt * 16 + q * 4 + r;
        size_t idx = (size_t)ch * N_ROWS + row;
        cs1[idx] = a1v; cs2[idx] = a2v; cidx[idx] = ai;
      }
    }
}

// ================= Kernel C: merge chunks; label + compact flagged-row list ==========
// Rigorous data-dependent margin: score error E <= 2^-16.4*T*C + 2^-19*C^2 per book;
// a wrong unflagged label requires gap >= 2E. margin = 2^-13*maxT*maxC + 1e-4 >= 5x that.
__global__ __launch_bounds__(256) void reduce_kernel(const float* __restrict__ cs1,
                                                     const float* __restrict__ cs2,
                                                     const int* __restrict__ cidx,
                                                     const int* __restrict__ gmaxT2,
                                                     const int* __restrict__ gmaxC2,
                                                     int* __restrict__ out,
                                                     int* __restrict__ list,
                                                     int* __restrict__ nflag) {
  const int r = blockIdx.x * 256 + threadIdx.x;
  const float margin =
      1.220703125e-4f * sqrtf(__int_as_float(*gmaxT2) * __int_as_float(*gmaxC2)) + 1.0e-4f;
  float S1 = -3.4e38f, S2 = -3.4e38f;
  int I = 0;
#pragma unroll
  for (int ch = 0; ch < SC_NCH; ch++) {  // ascending + strict '>' => min index on ties
    size_t idx = (size_t)ch * N_ROWS + r;
    float v1 = cs1[idx], v2 = cs2[idx];
    if (v1 > S1) {
      S2 = fmaxf(S1, v2); S1 = v1; I = cidx[idx];
    } else {
      S2 = fmaxf(S2, v1);
    }
  }
  out[r] = I;
  if (S1 - S2 < margin) {
    int slot = atomicAdd(nflag, 1);
    list[slot] = r;
  }
}

// ================= Kernel D: exact fp64 rescore of listed rows (grid-parallel) ========
__global__ __launch_bounds__(256) void fb_kernel(const int* __restrict__ list,
                                                 const int* __restrict__ nflag,
                                                 const float* __restrict__ x,
                                                 const float* __restrict__ w,
                                                 const float* __restrict__ codebook,
                                                 int* __restrict__ out) {
  __shared__ double ps[16][17];
  __shared__ double tsh[16];
  __shared__ double rs[256];
  __shared__ int ri[256];
  const int tid = threadIdx.x;
  const int cnt = *nflag;
  for (int i = blockIdx.x; i < cnt; i += gridDim.x) {
    const int row = list[i];
    {  // exact fp64 t = x_row . W^T
      int o = tid & 15, c = tid >> 4;
      double p = 0.0;
      for (int k = 0; k < 20; k++) {
        int d = c * 20 + k;
        p = fma((double)x[(size_t)row * D_IN + d], (double)w[o * D_IN + d], p);
      }
      ps[c][o] = p;
    }
    __syncthreads();
    if (tid < 16) {
      double t = 0.0;
      for (int c = 0; c < 16; c++) t += ps[c][tid];
      tsh[tid] = t;
    }
    __syncthreads();
    double t[16];
#pragma unroll
    for (int k = 0; k < 16; k++) t[k] = tsh[k];
    double bs = -1.0e300;
    int bi = 0;
    for (int j = tid; j < N_BOOKS; j += 256) {
      const float* cp = codebook + (size_t)j * CB;
      double dot = 0.0, cc = 0.0;
#pragma unroll
      for (int k = 0; k < 16; k++) {
        double cv = (double)cp[k];
        dot = fma(t[k], cv, dot);
        cc = fma(cv, cv, cc);
      }
      double mv = dot - 0.5 * cc;
      if (mv > bs) { bs = mv; bi = j; }  // ascending j: first wins
    }
    rs[tid] = bs; ri[tid] = bi;
    __syncthreads();
    for (int s = 128; s > 0; s >>= 1) {
      if (tid < s) {
        double os = rs[tid + s]; int oi = ri[tid + s];
        if (os > rs[tid] || (os == rs[tid] && oi < ri[tid])) { rs[tid] = os; ri[tid] = oi; }
      }
      __syncthreads();
    }
    if (tid == 0) out[row] = ri[0];
    __syncthreads();
  }
}

extern "C" void kernel_launch(void* const* d_in, const int* in_sizes, int n_in,
                              void* d_out, int out_size, void* d_ws, size_t ws_size,
                              hipStream_t stream) {
  (void)in_sizes; (void)n_in; (void)out_size; (void)ws_size;
  const float* x = (const float*)d_in[0];
  // d_in[1] = mask_time_indices: all-ones -> flatten; unused
  const float* w = (const float*)d_in[2];
  const float* codebook = (const float*)d_in[3];

  char* ws = (char*)d_ws;
  short* tsplit = (short*)(ws);               // 2 MB   @0
  short* bfrag = (short*)(ws + (2 << 20));    // 512 KB @2M
  float* nh_g = (float*)(ws + 2621440);       // 32 KB  @2.5M
  float* cs1 = (float*)(ws + (3 << 20));      // 1 MB   @3M
  float* cs2 = (float*)(ws + (5 << 20));      // 1 MB   @5M
  int* cidx = (int*)(ws + (7 << 20));         // 1 MB   @7M
  int* list = (int*)(ws + (9 << 20));         // 128 KB @9M
  int* scalars = (int*)(ws + (9 << 20) + (128 << 10));  // nflag, gmaxT2, gmaxC2
  int* nflag = scalars;
  int* gmaxT2 = scalars + 1;
  int* gmaxC2 = scalars + 2;
  int* out = (int*)d_out;

  hipMemsetAsync(scalars, 0, 3 * sizeof(int), stream);
  prep_proj_kernel<<<32 + N_ROWS / 64, 256, 0, stream>>>(codebook, x, w, bfrag, nh_g, tsplit,
                                                         gmaxT2, gmaxC2);
  score_kernel<<<128 * SC_NCH, 256, 0, stream>>>(tsplit, bfrag, nh_g, cs1, cs2, cidx);
  reduce_kernel<<<N_ROWS / 256, 256, 0, stream>>>(cs1, cs2, cidx, gmaxT2, gmaxC2, out, list, nflag);
  fb_kernel<<<64, 256, 0, stream>>>(list, nflag, x, w, codebook, out);
}